// Round 1
// baseline (267.532 us; speedup 1.0000x reference)
//
#include <hip/hip_runtime.h>

typedef __bf16 bf16_t;
typedef bf16_t bf16x8 __attribute__((ext_vector_type(8)));
typedef float f32x4 __attribute__((ext_vector_type(4)));

#define SEQLEN 2048
#define EMB 1024
#define NHEADS 16
#define N3 3072
#define NBATCH 2
#define NEG_INF (-__builtin_inff())

// ---------------------------------------------------------------------------
// Transpose + fp32->bf16 convert: W [K][N] fp32 -> Wt [N][K] bf16
// ---------------------------------------------------------------------------
__global__ __launch_bounds__(256) void transpose_w_bf16(
    const float* __restrict__ W, bf16_t* __restrict__ Wt, int K, int N)
{
    __shared__ float tile[64][65];
    const int n0 = blockIdx.x * 64, k0 = blockIdx.y * 64;
    const int t = threadIdx.x;
    const int nl = t & 63, k4 = t >> 6;
#pragma unroll
    for (int i = 0; i < 16; ++i) {
        int kk = k4 + i * 4;
        tile[kk][nl] = W[(size_t)(k0 + kk) * N + n0 + nl];
    }
    __syncthreads();
    const int kl = t & 63, n4 = t >> 6;
#pragma unroll
    for (int i = 0; i < 16; ++i) {
        int nn = n4 + i * 4;
        Wt[(size_t)(n0 + nn) * K + k0 + kl] = (bf16_t)tile[kl][nn];
    }
}

// ---------------------------------------------------------------------------
// GEMM: C[M][N] = A[M][K] @ Bt[N][K]^T + bias.  128x128 tile, BK=32,
// 4 waves (2x2), each wave 64x64 via 4x4 mfma_f32_16x16x32_bf16 frags.
// Reg-staged double-buffered LDS, one barrier per K-step.
// ---------------------------------------------------------------------------
template<bool A_F32, bool OUT_BF16>
__global__ __launch_bounds__(256) void gemm_bt_kernel(
    const void* __restrict__ Ap, const bf16_t* __restrict__ Bt,
    const float* __restrict__ bias, void* __restrict__ Cp,
    int Mdim, int Ndim, int Kdim)
{
    __shared__ bf16_t As[2][128 * 32];
    __shared__ bf16_t Bs[2][128 * 32];
    const int nb = Ndim >> 7;
    const int bx = blockIdx.x % nb, by = blockIdx.x / nb;
    const int r0 = by << 7, c0 = bx << 7;
    const int t = threadIdx.x, lane = t & 63;
    const int wid = t >> 6;
    const int wm = wid >> 1, wn = wid & 1;
    const int lr = lane & 15, lg = lane >> 4;
    const int srow = t >> 1, skk = (t & 1) << 4;   // 2 threads/row, 16 elems each

    f32x4 acc[4][4] = {};

    auto stage = [&](int buf, int kt) {
        const int k0 = kt << 5;
        bf16_t bv[16];
        if (A_F32) {
            const float* A = (const float*)Ap;
            const float* src = &A[(size_t)(r0 + srow) * Kdim + k0 + skk];
            float fv[16];
#pragma unroll
            for (int i = 0; i < 4; ++i)
                *(float4*)&fv[i * 4] = *(const float4*)&src[i * 4];
#pragma unroll
            for (int i = 0; i < 16; ++i) bv[i] = (bf16_t)fv[i];
        } else {
            const bf16_t* A = (const bf16_t*)Ap;
            const bf16_t* src = &A[(size_t)(r0 + srow) * Kdim + k0 + skk];
            *(float4*)&bv[0] = *(const float4*)&src[0];
            *(float4*)&bv[8] = *(const float4*)&src[8];
        }
        *(float4*)&As[buf][srow * 32 + skk]     = *(float4*)&bv[0];
        *(float4*)&As[buf][srow * 32 + skk + 8] = *(float4*)&bv[8];
        const bf16_t* bsrc = &Bt[(size_t)(c0 + srow) * Kdim + k0 + skk];
        *(float4*)&bv[0] = *(const float4*)&bsrc[0];
        *(float4*)&bv[8] = *(const float4*)&bsrc[8];
        *(float4*)&Bs[buf][srow * 32 + skk]     = *(float4*)&bv[0];
        *(float4*)&Bs[buf][srow * 32 + skk + 8] = *(float4*)&bv[8];
    };

    stage(0, 0);
    __syncthreads();
    int cur = 0;
    const int KT = Kdim >> 5;
    for (int kt = 0; kt < KT; ++kt) {
        if (kt + 1 < KT) stage(cur ^ 1, kt + 1);
        bf16x8 af[4], bfm[4];
#pragma unroll
        for (int m = 0; m < 4; ++m)
            af[m] = *(const bf16x8*)&As[cur][(wm * 64 + m * 16 + lr) * 32 + lg * 8];
#pragma unroll
        for (int n = 0; n < 4; ++n)
            bfm[n] = *(const bf16x8*)&Bs[cur][(wn * 64 + n * 16 + lr) * 32 + lg * 8];
#pragma unroll
        for (int m = 0; m < 4; ++m)
#pragma unroll
            for (int n = 0; n < 4; ++n)
                acc[m][n] = __builtin_amdgcn_mfma_f32_16x16x32_bf16(
                    af[m], bfm[n], acc[m][n], 0, 0, 0);
        __syncthreads();
        cur ^= 1;
    }

#pragma unroll
    for (int m = 0; m < 4; ++m) {
#pragma unroll
        for (int n = 0; n < 4; ++n) {
            const int col = c0 + wn * 64 + n * 16 + lr;
            const float bval = bias[col];
#pragma unroll
            for (int j = 0; j < 4; ++j) {
                const int row = r0 + wm * 64 + m * 16 + lg * 4 + j;
                const float v = acc[m][n][j] + bval;
                if (OUT_BF16)
                    ((bf16_t*)Cp)[(size_t)row * Ndim + col] = (bf16_t)v;
                else
                    ((float*)Cp)[(size_t)row * Ndim + col] = v;
            }
        }
    }
}

// ---------------------------------------------------------------------------
// Causal flash attention. qkv bf16 [B*S][3072] (Q|K|V, head-major cols).
// 1 block = one (b,h) and 64 q-rows; 4 waves x 16 q-rows.
// KBLK=64. Online softmax in registers; P via padded LDS for PV A-frags.
// ---------------------------------------------------------------------------
__global__ __launch_bounds__(256) void attn_kernel(
    const bf16_t* __restrict__ qkv, bf16_t* __restrict__ attn_out)
{
    __shared__ bf16_t Kl[64 * 72];       // K rows [kp][d], pad 72
    __shared__ bf16_t Vt[64 * 72];       // V^T [d][kp], pad 72
    __shared__ bf16_t Pl[4][16 * 72];    // per-wave P [q][kp], pad 72
    const int bh = blockIdx.x >> 5, qt = blockIdx.x & 31;
    const int b = bh >> 4, h = bh & 15;
    const int q0 = qt << 6;
    const int t = threadIdx.x, lane = t & 63, wid = t >> 6;
    const int lr = lane & 15, lg = lane >> 4;

    // Q fragments held in registers for the whole block
    bf16x8 qa[2];
    {
        const int qrow = q0 + wid * 16 + lr;
        const bf16_t* qbase = &qkv[(size_t)(b * SEQLEN + qrow) * N3 + h * 64];
        qa[0] = *(const bf16x8*)&qbase[lg * 8];
        qa[1] = *(const bf16x8*)&qbase[32 + lg * 8];
    }

    f32x4 o[4] = {};
    float mstat[4] = {NEG_INF, NEG_INF, NEG_INF, NEG_INF};
    float lstat[4] = {0.f, 0.f, 0.f, 0.f};

    const int skp = t >> 2, sdc = (t & 3) << 4;  // staging: 4 thr/row, 16 elems

    for (int kt = 0; kt <= qt; ++kt) {
        // ---- stage K tile and V^T tile ----
        {
            const bf16_t* ksrc =
                &qkv[(size_t)(b * SEQLEN + kt * 64 + skp) * N3 + EMB + h * 64 + sdc];
            float4 ka = *(const float4*)ksrc;
            float4 kb = *(const float4*)(ksrc + 8);
            *(float4*)&Kl[skp * 72 + sdc]     = ka;
            *(float4*)&Kl[skp * 72 + sdc + 8] = kb;
            bf16_t vv[16];
            const bf16_t* vsrc = ksrc + EMB;
            *(float4*)&vv[0] = *(const float4*)vsrc;
            *(float4*)&vv[8] = *(const float4*)(vsrc + 8);
#pragma unroll
            for (int j2 = 0; j2 < 16; ++j2) {
                int jj = (j2 + skp) & 15;      // stagger to spread banks
                Vt[(sdc + jj) * 72 + skp] = vv[jj];
            }
        }
        __syncthreads();

        // ---- QK^T (16 q x 64 kp per wave) ----
        f32x4 sc[4];
#pragma unroll
        for (int n = 0; n < 4; ++n)
#pragma unroll
            for (int j = 0; j < 4; ++j) sc[n][j] = 0.f;
#pragma unroll
        for (int s = 0; s < 2; ++s) {
#pragma unroll
            for (int n = 0; n < 4; ++n) {
                bf16x8 kb = *(const bf16x8*)&Kl[(n * 16 + lr) * 72 + s * 32 + lg * 8];
                sc[n] = __builtin_amdgcn_mfma_f32_16x16x32_bf16(qa[s], kb, sc[n], 0, 0, 0);
            }
        }

        // ---- scale + causal mask + online softmax ----
        float pmax[4] = {NEG_INF, NEG_INF, NEG_INF, NEG_INF};
#pragma unroll
        for (int n = 0; n < 4; ++n) {
            const int kpg = kt * 64 + n * 16 + lr;
#pragma unroll
            for (int j = 0; j < 4; ++j) {
                const int qg = q0 + wid * 16 + lg * 4 + j;
                float v = sc[n][j] * 0.125f;
                v = (kpg <= qg) ? v : NEG_INF;
                sc[n][j] = v;
                pmax[j] = fmaxf(pmax[j], v);
            }
        }
#pragma unroll
        for (int j = 0; j < 4; ++j) {
            float v = pmax[j];
            v = fmaxf(v, __shfl_xor(v, 1));
            v = fmaxf(v, __shfl_xor(v, 2));
            v = fmaxf(v, __shfl_xor(v, 4));
            v = fmaxf(v, __shfl_xor(v, 8));
            pmax[j] = v;
        }
        float alpha[4];
#pragma unroll
        for (int j = 0; j < 4; ++j) {
            float mn = fmaxf(mstat[j], pmax[j]);
            alpha[j] = __expf(mstat[j] - mn);
            mstat[j] = mn;
        }
        float rs[4] = {0.f, 0.f, 0.f, 0.f};
#pragma unroll
        for (int n = 0; n < 4; ++n)
#pragma unroll
            for (int j = 0; j < 4; ++j) {
                float p = __expf(sc[n][j] - mstat[j]);
                sc[n][j] = p;
                rs[j] += p;
            }
#pragma unroll
        for (int j = 0; j < 4; ++j) {
            float v = rs[j];
            v += __shfl_xor(v, 1);
            v += __shfl_xor(v, 2);
            v += __shfl_xor(v, 4);
            v += __shfl_xor(v, 8);
            lstat[j] = lstat[j] * alpha[j] + v;
        }
#pragma unroll
        for (int dn = 0; dn < 4; ++dn)
#pragma unroll
            for (int j = 0; j < 4; ++j) o[dn][j] *= alpha[j];

        // ---- P -> LDS (wave-private, no barrier needed) ----
#pragma unroll
        for (int n = 0; n < 4; ++n)
#pragma unroll
            for (int j = 0; j < 4; ++j)
                Pl[wid][(lg * 4 + j) * 72 + n * 16 + lr] = (bf16_t)sc[n][j];

        // ---- PV ----
#pragma unroll
        for (int s2 = 0; s2 < 2; ++s2) {
            bf16x8 pa = *(const bf16x8*)&Pl[wid][lr * 72 + s2 * 32 + lg * 8];
#pragma unroll
            for (int dn = 0; dn < 4; ++dn) {
                bf16x8 vb = *(const bf16x8*)&Vt[(dn * 16 + lr) * 72 + s2 * 32 + lg * 8];
                o[dn] = __builtin_amdgcn_mfma_f32_16x16x32_bf16(pa, vb, o[dn], 0, 0, 0);
            }
        }
        __syncthreads();
    }

    // ---- epilogue: normalize, write attn_out [B*S][E] (col = h*64 + d) ----
#pragma unroll
    for (int dn = 0; dn < 4; ++dn) {
#pragma unroll
        for (int j = 0; j < 4; ++j) {
            const int qg = q0 + wid * 16 + lg * 4 + j;
            const float outv = o[dn][j] / lstat[j];
            attn_out[(size_t)(b * SEQLEN + qg) * EMB + h * 64 + dn * 16 + lr] =
                (bf16_t)outv;
        }
    }
}

// ---------------------------------------------------------------------------
extern "C" void kernel_launch(void* const* d_in, const int* in_sizes, int n_in,
                              void* d_out, int out_size, void* d_ws, size_t ws_size,
                              hipStream_t stream)
{
    const float* X     = (const float*)d_in[0];   // [2,2048,1024]
    const float* W_qkv = (const float*)d_in[1];   // [1024,3072]
    const float* b_qkv = (const float*)d_in[2];   // [3072]
    const float* W_out = (const float*)d_in[3];   // [1024,1024]
    const float* b_out = (const float*)d_in[4];   // [1024]
    float* out = (float*)d_out;

    char* ws = (char*)d_ws;
    bf16_t* Wqkv_t = (bf16_t*)ws;                           //  6 MB [3072][1024]
    bf16_t* Wout_t = (bf16_t*)(ws + 6u * 1024 * 1024);      //  2 MB [1024][1024]
    bf16_t* qkv    = (bf16_t*)(ws + 8u * 1024 * 1024);      // 24 MB [4096][3072]
    bf16_t* attn   = (bf16_t*)(ws + 32u * 1024 * 1024);     //  8 MB [4096][1024]

    dim3 blk(256);
    transpose_w_bf16<<<dim3(N3 / 64, EMB / 64), blk, 0, stream>>>(W_qkv, Wqkv_t, EMB, N3);
    transpose_w_bf16<<<dim3(EMB / 64, EMB / 64), blk, 0, stream>>>(W_out, Wout_t, EMB, EMB);

    // qkv = X @ W_qkv + b_qkv   (M=4096, N=3072, K=1024), bf16 out
    gemm_bt_kernel<true, true><<<(4096 / 128) * (N3 / 128), blk, 0, stream>>>(
        (const void*)X, Wqkv_t, b_qkv, (void*)qkv, 4096, N3, EMB);

    // causal flash attention -> attn [4096][1024] bf16
    attn_kernel<<<NBATCH * NHEADS * (SEQLEN / 64), blk, 0, stream>>>(qkv, attn);

    // out = attn @ W_out + b_out  (M=4096, N=1024, K=1024), fp32 out
    gemm_bt_kernel<false, false><<<(4096 / 128) * (EMB / 128), blk, 0, stream>>>(
        (const void*)attn, Wout_t, b_out, (void*)out, 4096, EMB, EMB);
}

// Round 2
// 145.573 us; speedup vs baseline: 1.8378x; 1.8378x over previous
//
#include <hip/hip_runtime.h>

typedef __bf16 bf16_t;
typedef bf16_t bf16x8 __attribute__((ext_vector_type(8)));
typedef bf16_t bf16x4 __attribute__((ext_vector_type(4)));
typedef float f32x4 __attribute__((ext_vector_type(4)));

#define SEQLEN 2048
#define EMB 1024
#define NHEADS 16
#define N3 3072
#define NBATCH 2
#define NEG_INF (-__builtin_inff())
#define SC2 0.18033688011112042f   // 0.125 * log2(e): softmax in exp2 domain

// ---------------------------------------------------------------------------
// Transpose + fp32->bf16 convert: W [K][N] fp32 -> Wt [N][K] bf16
// ---------------------------------------------------------------------------
__global__ __launch_bounds__(256) void transpose_w_bf16(
    const float* __restrict__ W, bf16_t* __restrict__ Wt, int K, int N)
{
    __shared__ float tile[64][65];
    const int n0 = blockIdx.x * 64, k0 = blockIdx.y * 64;
    const int t = threadIdx.x;
    const int nl = t & 63, k4 = t >> 6;
#pragma unroll
    for (int i = 0; i < 16; ++i) {
        int kk = k4 + i * 4;
        tile[kk][nl] = W[(size_t)(k0 + kk) * N + n0 + nl];
    }
    __syncthreads();
    const int kl = t & 63, n4 = t >> 6;
#pragma unroll
    for (int i = 0; i < 16; ++i) {
        int nn = n4 + i * 4;
        Wt[(size_t)(n0 + nn) * K + k0 + kl] = (bf16_t)tile[kl][nn];
    }
}

// ---------------------------------------------------------------------------
// fp32 -> bf16 convert (X pre-convert), 8 elems/thread
// ---------------------------------------------------------------------------
__global__ __launch_bounds__(256) void cvt_f32_bf16(
    const float* __restrict__ in, bf16_t* __restrict__ out, int n)
{
    const int i = (blockIdx.x * 256 + threadIdx.x) * 8;
    if (i >= n) return;
    float4 a = *(const float4*)&in[i];
    float4 b = *(const float4*)&in[i + 4];
    bf16_t v[8];
    v[0] = (bf16_t)a.x; v[1] = (bf16_t)a.y; v[2] = (bf16_t)a.z; v[3] = (bf16_t)a.w;
    v[4] = (bf16_t)b.x; v[5] = (bf16_t)b.y; v[6] = (bf16_t)b.z; v[7] = (bf16_t)b.w;
    *(float4*)&out[i] = *(float4*)&v[0];
}

// ---------------------------------------------------------------------------
// Extract V from qkv and transpose: vt[bh][d=64][s=2048]
// ---------------------------------------------------------------------------
__global__ __launch_bounds__(256) void v_transpose(
    const bf16_t* __restrict__ qkv, bf16_t* __restrict__ vt)
{
    __shared__ bf16_t tile[64][72];
    const int bh = blockIdx.x & 31, st = blockIdx.x >> 5;
    const int b = bh >> 4, h = bh & 15;
    const int t = threadIdx.x;
    const int sr = t >> 2, dc = (t & 3) << 4;
    const bf16_t* src = &qkv[(size_t)(b * SEQLEN + st * 64 + sr) * N3 + 2 * EMB + h * 64 + dc];
    *(float4*)&tile[sr][dc]     = *(const float4*)src;
    *(float4*)&tile[sr][dc + 8] = *(const float4*)(src + 8);
    __syncthreads();
    const int d = t >> 2, scol = (t & 3) << 4;
    bf16_t v[16];
#pragma unroll
    for (int i = 0; i < 16; ++i) v[i] = tile[scol + i][d];
    bf16_t* dst = &vt[(size_t)(bh * 64 + d) * SEQLEN + st * 64 + scol];
    *(float4*)&dst[0] = *(float4*)&v[0];
    *(float4*)&dst[8] = *(float4*)&v[8];
}

// ---------------------------------------------------------------------------
// GEMM: C[M][N] = A[M][K](bf16) @ Bt[N][K]^T + bias.  128x128 tile, BK=32.
// ---------------------------------------------------------------------------
template<bool OUT_BF16>
__global__ __launch_bounds__(256) void gemm_bt_kernel(
    const bf16_t* __restrict__ A, const bf16_t* __restrict__ Bt,
    const float* __restrict__ bias, void* __restrict__ Cp,
    int Mdim, int Ndim, int Kdim)
{
    __shared__ bf16_t As[2][128 * 32];
    __shared__ bf16_t Bs[2][128 * 32];
    const int nb = Ndim >> 7;
    const int bx = blockIdx.x % nb, by = blockIdx.x / nb;
    const int r0 = by << 7, c0 = bx << 7;
    const int t = threadIdx.x, lane = t & 63;
    const int wid = t >> 6;
    const int wm = wid >> 1, wn = wid & 1;
    const int lr = lane & 15, lg = lane >> 4;
    const int srow = t >> 1, skk = (t & 1) << 4;

    f32x4 acc[4][4] = {};

    auto stage = [&](int buf, int kt) {
        const int k0 = kt << 5;
        bf16_t bv[16];
        const bf16_t* src = &A[(size_t)(r0 + srow) * Kdim + k0 + skk];
        *(float4*)&bv[0] = *(const float4*)&src[0];
        *(float4*)&bv[8] = *(const float4*)&src[8];
        *(float4*)&As[buf][srow * 32 + skk]     = *(float4*)&bv[0];
        *(float4*)&As[buf][srow * 32 + skk + 8] = *(float4*)&bv[8];
        const bf16_t* bsrc = &Bt[(size_t)(c0 + srow) * Kdim + k0 + skk];
        *(float4*)&bv[0] = *(const float4*)&bsrc[0];
        *(float4*)&bv[8] = *(const float4*)&bsrc[8];
        *(float4*)&Bs[buf][srow * 32 + skk]     = *(float4*)&bv[0];
        *(float4*)&Bs[buf][srow * 32 + skk + 8] = *(float4*)&bv[8];
    };

    stage(0, 0);
    __syncthreads();
    int cur = 0;
    const int KT = Kdim >> 5;
    for (int kt = 0; kt < KT; ++kt) {
        if (kt + 1 < KT) stage(cur ^ 1, kt + 1);
        bf16x8 af[4], bfm[4];
#pragma unroll
        for (int m = 0; m < 4; ++m)
            af[m] = *(const bf16x8*)&As[cur][(wm * 64 + m * 16 + lr) * 32 + lg * 8];
#pragma unroll
        for (int n = 0; n < 4; ++n)
            bfm[n] = *(const bf16x8*)&Bs[cur][(wn * 64 + n * 16 + lr) * 32 + lg * 8];
#pragma unroll
        for (int m = 0; m < 4; ++m)
#pragma unroll
            for (int n = 0; n < 4; ++n)
                acc[m][n] = __builtin_amdgcn_mfma_f32_16x16x32_bf16(
                    af[m], bfm[n], acc[m][n], 0, 0, 0);
        __syncthreads();
        cur ^= 1;
    }

#pragma unroll
    for (int m = 0; m < 4; ++m) {
#pragma unroll
        for (int n = 0; n < 4; ++n) {
            const int col = c0 + wn * 64 + n * 16 + lr;
            const float bval = bias[col];
#pragma unroll
            for (int j = 0; j < 4; ++j) {
                const int row = r0 + wm * 64 + m * 16 + lg * 4 + j;
                const float v = acc[m][n][j] + bval;
                if (OUT_BF16)
                    ((bf16_t*)Cp)[(size_t)row * Ndim + col] = (bf16_t)v;
                else
                    ((float*)Cp)[(size_t)row * Ndim + col] = v;
            }
        }
    }
}

// ---------------------------------------------------------------------------
// Causal flash attention v2.
//  - swapped QK^T: sc = mfma(K_frag, Q_frag) -> S^T[k][q]; softmax per-lane.
//  - K tile [64][64] and V^T tile [64][64] in LDS, XOR-swizzled (T2/G4).
//  - double-buffered staging, 1 barrier/iter, issue-early/write-late (T14).
//  - block = (bh, pair p): q-tiles {p, 31-p} -> uniform 33 steps/block.
// ---------------------------------------------------------------------------
__device__ __forceinline__ void st16s(bf16_t* base, int r, int c, float4 v) {
    const int byte = (r * 128 + c * 2) ^ ((r & 7) << 4);
    *(float4*)((char*)base + byte) = v;
}
__device__ __forceinline__ void st8s(bf16_t* base, int r, int c, bf16x4 v) {
    const int byte = (r * 128 + c * 2) ^ ((r & 7) << 4);
    *(bf16x4*)((char*)base + byte) = v;
}
__device__ __forceinline__ bf16x8 ld16s(const bf16_t* base, int r, int c) {
    const int byte = (r * 128 + c * 2) ^ ((r & 7) << 4);
    return *(const bf16x8*)((const char*)base + byte);
}

__global__ __launch_bounds__(256) void attn_kernel(
    const bf16_t* __restrict__ qkv, const bf16_t* __restrict__ vt,
    bf16_t* __restrict__ attn_out)
{
    __shared__ bf16_t Kl[2][64 * 64];
    __shared__ bf16_t Vl[2][64 * 64];
    __shared__ bf16_t Pl[4][16 * 64];
    const int bh = blockIdx.x & 31, pr = blockIdx.x >> 5;
    const int b = bh >> 4, h = bh & 15;
    const int t = threadIdx.x, lane = t & 63, wid = t >> 6;
    const int lr = lane & 15, lg = lane >> 4;
    const int sr = t >> 2, sc16 = (t & 3) << 4;

    const bf16_t* kbase = &qkv[(size_t)(b * SEQLEN) * N3 + EMB + h * 64];
    const bf16_t* vbase = &vt[(size_t)(bh * 64) * SEQLEN];

    auto ldK = [&](int kt, float4& a, float4& c) {
        const bf16_t* p = &kbase[(size_t)(kt * 64 + sr) * N3 + sc16];
        a = *(const float4*)p; c = *(const float4*)(p + 8);
    };
    auto ldV = [&](int kt, float4& a, float4& c) {
        const bf16_t* p = &vbase[(size_t)sr * SEQLEN + kt * 64 + sc16];
        a = *(const float4*)p; c = *(const float4*)(p + 8);
    };
    auto stKV = [&](int buf, float4 k0, float4 k1, float4 v0, float4 v1) {
        st16s(Kl[buf], sr, sc16, k0); st16s(Kl[buf], sr, sc16 + 8, k1);
        st16s(Vl[buf], sr, sc16, v0); st16s(Vl[buf], sr, sc16 + 8, v1);
    };

    for (int phase = 0; phase < 2; ++phase) {
        const int qt = phase ? 31 - pr : pr;
        const int q0 = qt << 6;
        const int qg = q0 + wid * 16 + lr;     // this lane's q row (S^T layout)

        bf16x8 qa0, qa1;
        {
            const bf16_t* qb = &qkv[(size_t)(b * SEQLEN + qg) * N3 + h * 64];
            qa0 = *(const bf16x8*)&qb[lg * 8];
            qa1 = *(const bf16x8*)&qb[32 + lg * 8];
        }
        f32x4 o[4] = {};
        float m_run = NEG_INF, l_run = 0.f;

        {   // prologue: stage kt=0 into buf 0
            float4 k0, k1, v0, v1;
            ldK(0, k0, k1); ldV(0, v0, v1);
            stKV(0, k0, k1, v0, v1);
        }
        __syncthreads();
        int cur = 0;
        for (int kt = 0; kt <= qt; ++kt) {
            // T14 issue-early: next tile's global loads
            float4 nk0, nk1, nv0, nv1;
            const bool more = (kt < qt);
            if (more) { ldK(kt + 1, nk0, nk1); ldV(kt + 1, nv0, nv1); }

            // QK^T (swapped): sc[n][j] = S[k = kt*64+16n+4*lg+j][q = qg]
            f32x4 sc[4] = {};
#pragma unroll
            for (int n = 0; n < 4; ++n) {
                bf16x8 kb0 = ld16s(Kl[cur], n * 16 + lr, lg * 8);
                bf16x8 kb1 = ld16s(Kl[cur], n * 16 + lr, 32 + lg * 8);
                sc[n] = __builtin_amdgcn_mfma_f32_16x16x32_bf16(kb0, qa0, sc[n], 0, 0, 0);
                sc[n] = __builtin_amdgcn_mfma_f32_16x16x32_bf16(kb1, qa1, sc[n], 0, 0, 0);
            }

            // scale (+mask on diagonal tile only) + per-lane row max
            float pmax = NEG_INF;
            if (kt == qt) {
#pragma unroll
                for (int n = 0; n < 4; ++n)
#pragma unroll
                    for (int j = 0; j < 4; ++j) {
                        const int kg = kt * 64 + n * 16 + lg * 4 + j;
                        float v = sc[n][j] * SC2;
                        v = (kg <= qg) ? v : NEG_INF;
                        sc[n][j] = v;
                        pmax = fmaxf(pmax, v);
                    }
            } else {
#pragma unroll
                for (int n = 0; n < 4; ++n)
#pragma unroll
                    for (int j = 0; j < 4; ++j) {
                        float v = sc[n][j] * SC2;
                        sc[n][j] = v;
                        pmax = fmaxf(pmax, v);
                    }
            }
            pmax = fmaxf(pmax, __shfl_xor(pmax, 16));
            pmax = fmaxf(pmax, __shfl_xor(pmax, 32));
            const float mnew = fmaxf(m_run, pmax);
            const float alpha = exp2f(m_run - mnew);
            m_run = mnew;
            float rs = 0.f;
#pragma unroll
            for (int n = 0; n < 4; ++n)
#pragma unroll
                for (int j = 0; j < 4; ++j) {
                    float p = exp2f(sc[n][j] - mnew);
                    sc[n][j] = p;
                    rs += p;
                }
            rs += __shfl_xor(rs, 16);
            rs += __shfl_xor(rs, 32);
            l_run = l_run * alpha + rs;

            // rescale O (o rows are q = lg*4+j -> broadcast alpha from lane q)
            float al[4];
#pragma unroll
            for (int j = 0; j < 4; ++j) al[j] = __shfl(alpha, lg * 4 + j);
#pragma unroll
            for (int dn = 0; dn < 4; ++dn)
#pragma unroll
                for (int j = 0; j < 4; ++j) o[dn][j] *= al[j];

            // P -> LDS [q][k], packed b64 (k-consecutive per lane)
#pragma unroll
            for (int n = 0; n < 4; ++n) {
                bf16x4 pk;
#pragma unroll
                for (int j = 0; j < 4; ++j) pk[j] = (bf16_t)sc[n][j];
                st8s(Pl[wid], lr, n * 16 + lg * 4, pk);
            }

            // PV: o[dn] (q = lg*4+j rows, d = dn*16+lr cols)
#pragma unroll
            for (int s2 = 0; s2 < 2; ++s2) {
                bf16x8 pa = ld16s(Pl[wid], lr, s2 * 32 + lg * 8);
#pragma unroll
                for (int dn = 0; dn < 4; ++dn) {
                    bf16x8 vb = ld16s(Vl[cur], dn * 16 + lr, s2 * 32 + lg * 8);
                    o[dn] = __builtin_amdgcn_mfma_f32_16x16x32_bf16(pa, vb, o[dn], 0, 0, 0);
                }
            }

            // write-late: commit next tile into the other buffer
            if (more) stKV(cur ^ 1, nk0, nk1, nv0, nv1);
            __syncthreads();
            cur ^= 1;
        }

        // epilogue
        float li[4];
#pragma unroll
        for (int j = 0; j < 4; ++j) li[j] = 1.0f / __shfl(l_run, lg * 4 + j);
#pragma unroll
        for (int dn = 0; dn < 4; ++dn)
#pragma unroll
            for (int j = 0; j < 4; ++j) {
                const int row = b * SEQLEN + q0 + wid * 16 + lg * 4 + j;
                attn_out[(size_t)row * EMB + h * 64 + dn * 16 + lr] =
                    (bf16_t)(o[dn][j] * li[j]);
            }
    }
}

// ---------------------------------------------------------------------------
extern "C" void kernel_launch(void* const* d_in, const int* in_sizes, int n_in,
                              void* d_out, int out_size, void* d_ws, size_t ws_size,
                              hipStream_t stream)
{
    const float* X     = (const float*)d_in[0];
    const float* W_qkv = (const float*)d_in[1];
    const float* b_qkv = (const float*)d_in[2];
    const float* W_out = (const float*)d_in[3];
    const float* b_out = (const float*)d_in[4];
    float* out = (float*)d_out;

    char* ws = (char*)d_ws;
    bf16_t* Wqkv_t = (bf16_t*)ws;                           //  6 MB [3072][1024]
    bf16_t* Wout_t = (bf16_t*)(ws + 6u * 1024 * 1024);      //  2 MB [1024][1024]
    bf16_t* qkv    = (bf16_t*)(ws + 8u * 1024 * 1024);      // 24 MB [4096][3072]
    bf16_t* attn   = (bf16_t*)(ws + 32u * 1024 * 1024);     //  8 MB [4096][1024]
    bf16_t* Xb     = (bf16_t*)(ws + 40u * 1024 * 1024);     //  8 MB [4096][1024]
    bf16_t* Vt_g   = (bf16_t*)(ws + 48u * 1024 * 1024);     //  8 MB [32][64][2048]

    dim3 blk(256);
    transpose_w_bf16<<<dim3(N3 / 64, EMB / 64), blk, 0, stream>>>(W_qkv, Wqkv_t, EMB, N3);
    transpose_w_bf16<<<dim3(EMB / 64, EMB / 64), blk, 0, stream>>>(W_out, Wout_t, EMB, EMB);
    cvt_f32_bf16<<<4096 * 1024 / (256 * 8), blk, 0, stream>>>(X, Xb, 4096 * 1024);

    // qkv = X @ W_qkv + b_qkv  (M=4096, N=3072, K=1024), bf16 out
    gemm_bt_kernel<true><<<(4096 / 128) * (N3 / 128), blk, 0, stream>>>(
        Xb, Wqkv_t, b_qkv, (void*)qkv, 4096, N3, EMB);

    // V extract+transpose -> [bh][64][2048]
    v_transpose<<<32 * (SEQLEN / 64), blk, 0, stream>>>(qkv, Vt_g);

    // causal flash attention -> attn [4096][1024] bf16
    attn_kernel<<<32 * 16, blk, 0, stream>>>(qkv, Vt_g, attn);

    // out = attn @ W_out + b_out  (M=4096, N=1024, K=1024), fp32 out
    gemm_bt_kernel<false><<<(4096 / 128) * (EMB / 128), blk, 0, stream>>>(
        attn, Wout_t, b_out, (void*)out, 4096, EMB, EMB);
}

// Round 3
// 132.984 us; speedup vs baseline: 2.0118x; 1.0947x over previous
//
#include <hip/hip_runtime.h>

typedef __bf16 bf16_t;
typedef bf16_t bf16x8 __attribute__((ext_vector_type(8)));
typedef bf16_t bf16x4 __attribute__((ext_vector_type(4)));
typedef float f32x4 __attribute__((ext_vector_type(4)));

#define SEQLEN 2048
#define EMB 1024
#define NHEADS 16
#define N3 3072
#define NBATCH 2
#define NEG_INF (-__builtin_inff())
#define SC2 0.18033688011112042f   // 0.125 * log2(e): softmax in exp2 domain

// async global->LDS, 16B per lane. LDS base must be wave-uniform.
__device__ __forceinline__ void async16(bf16_t* lds, const bf16_t* g) {
    __builtin_amdgcn_global_load_lds(
        (const __attribute__((address_space(1))) void*)g,
        (__attribute__((address_space(3))) void*)lds, 16, 0, 0);
}

// ---------------------------------------------------------------------------
// Transpose + fp32->bf16 convert: W [K][N] fp32 -> Wt [N][K] bf16.
// Rows n < scale_below are multiplied by SC2 (pre-scaled Q path).
// ---------------------------------------------------------------------------
__global__ __launch_bounds__(256) void transpose_w_bf16(
    const float* __restrict__ W, bf16_t* __restrict__ Wt, int K, int N,
    int scale_below)
{
    __shared__ float tile[64][65];
    const int n0 = blockIdx.x * 64, k0 = blockIdx.y * 64;
    const float s = (n0 < scale_below) ? SC2 : 1.0f;   // 64-aligned blocks don't straddle
    const int t = threadIdx.x;
    const int nl = t & 63, k4 = t >> 6;
#pragma unroll
    for (int i = 0; i < 16; ++i) {
        int kk = k4 + i * 4;
        tile[kk][nl] = W[(size_t)(k0 + kk) * N + n0 + nl];
    }
    __syncthreads();
    const int kl = t & 63, n4 = t >> 6;
#pragma unroll
    for (int i = 0; i < 16; ++i) {
        int nn = n4 + i * 4;
        Wt[(size_t)(n0 + nn) * K + k0 + kl] = (bf16_t)(tile[kl][nn] * s);
    }
}

__global__ __launch_bounds__(256) void scale_bias(
    const float* __restrict__ b, float* __restrict__ out)
{
    const int i = blockIdx.x * 256 + threadIdx.x;
    if (i < N3) out[i] = b[i] * (i < EMB ? SC2 : 1.0f);
}

// ---------------------------------------------------------------------------
// fp32 -> bf16 convert (X pre-convert), 8 elems/thread
// ---------------------------------------------------------------------------
__global__ __launch_bounds__(256) void cvt_f32_bf16(
    const float* __restrict__ in, bf16_t* __restrict__ out, int n)
{
    const int i = (blockIdx.x * 256 + threadIdx.x) * 8;
    if (i >= n) return;
    float4 a = *(const float4*)&in[i];
    float4 b = *(const float4*)&in[i + 4];
    bf16_t v[8];
    v[0] = (bf16_t)a.x; v[1] = (bf16_t)a.y; v[2] = (bf16_t)a.z; v[3] = (bf16_t)a.w;
    v[4] = (bf16_t)b.x; v[5] = (bf16_t)b.y; v[6] = (bf16_t)b.z; v[7] = (bf16_t)b.w;
    *(float4*)&out[i] = *(float4*)&v[0];
}

// ---------------------------------------------------------------------------
// Extract V from qkv and transpose: vt[bh][d=64][s=2048]
// ---------------------------------------------------------------------------
__global__ __launch_bounds__(256) void v_transpose(
    const bf16_t* __restrict__ qkv, bf16_t* __restrict__ vt)
{
    __shared__ bf16_t tile[64][72];
    const int bh = blockIdx.x & 31, st = blockIdx.x >> 5;
    const int b = bh >> 4, h = bh & 15;
    const int t = threadIdx.x;
    const int sr = t >> 2, dc = (t & 3) << 4;
    const bf16_t* src = &qkv[(size_t)(b * SEQLEN + st * 64 + sr) * N3 + 2 * EMB + h * 64 + dc];
    *(float4*)&tile[sr][dc]     = *(const float4*)src;
    *(float4*)&tile[sr][dc + 8] = *(const float4*)(src + 8);
    __syncthreads();
    const int d = t >> 2, scol = (t & 3) << 4;
    bf16_t v[16];
#pragma unroll
    for (int i = 0; i < 16; ++i) v[i] = tile[scol + i][d];
    bf16_t* dst = &vt[(size_t)(bh * 64 + d) * SEQLEN + st * 64 + scol];
    *(float4*)&dst[0] = *(float4*)&v[0];
    *(float4*)&dst[8] = *(float4*)&v[8];
}

// ---------------------------------------------------------------------------
// GEMM (m97 structure): C[M][N] = A[M][K](bf16) @ Bt[N][K]^T + bias.
// 128x128 tile, BK=32, global_load_lds width-16 staging, single buffer,
// 2 barriers per K-step. Bijective XCD swizzle (grid % 8 == 0 required).
// ---------------------------------------------------------------------------
template<bool OUT_BF16>
__global__ __launch_bounds__(256) void gemm_bt_kernel(
    const bf16_t* __restrict__ A, const bf16_t* __restrict__ Bt,
    const float* __restrict__ bias, void* __restrict__ Cp,
    int Mdim, int Ndim, int Kdim)
{
    __shared__ bf16_t As[128 * 32];
    __shared__ bf16_t Bs[128 * 32];
    const int nb = Ndim >> 7;
    const int cpx = gridDim.x >> 3;
    const int bid = (blockIdx.x & 7) * cpx + (blockIdx.x >> 3);
    const int bx = bid % nb, by = bid / nb;
    const int r0 = by << 7, c0 = bx << 7;
    const int t = threadIdx.x, lane = t & 63;
    const int wid = t >> 6;
    const int wm = wid >> 1, wn = wid & 1;
    const int lr = lane & 15, lg = lane >> 4;

    // staging geometry: wave w covers rows [w*32, w*32+32), lane -> (row, 8-col chunk)
    const int glrow = wid * 32 + (lane >> 2);
    const int glcol = (lane & 3) << 3;
    bf16_t* ldsA = &As[wid * 1024];
    bf16_t* ldsB = &Bs[wid * 1024];
    const bf16_t* gA = &A[(size_t)(r0 + glrow) * Kdim + glcol];
    const bf16_t* gB = &Bt[(size_t)(c0 + glrow) * Kdim + glcol];
    const size_t rowstep = (size_t)16 * Kdim;

    f32x4 acc[4][4] = {};
    const int KT = Kdim >> 5;
    for (int kt = 0; kt < KT; ++kt) {
        const int k0 = kt << 5;
        async16(ldsA,       gA + k0);
        async16(ldsA + 512, gA + k0 + rowstep);
        async16(ldsB,       gB + k0);
        async16(ldsB + 512, gB + k0 + rowstep);
        __syncthreads();   // drains vmcnt -> LDS tile ready
        bf16x8 af[4], bfm[4];
#pragma unroll
        for (int m = 0; m < 4; ++m)
            af[m] = *(const bf16x8*)&As[(wm * 64 + m * 16 + lr) * 32 + lg * 8];
#pragma unroll
        for (int n = 0; n < 4; ++n)
            bfm[n] = *(const bf16x8*)&Bs[(wn * 64 + n * 16 + lr) * 32 + lg * 8];
#pragma unroll
        for (int m = 0; m < 4; ++m)
#pragma unroll
            for (int n = 0; n < 4; ++n)
                acc[m][n] = __builtin_amdgcn_mfma_f32_16x16x32_bf16(
                    af[m], bfm[n], acc[m][n], 0, 0, 0);
        __syncthreads();   // reads done before next overwrite
    }

#pragma unroll
    for (int m = 0; m < 4; ++m) {
#pragma unroll
        for (int n = 0; n < 4; ++n) {
            const int col = c0 + wn * 64 + n * 16 + lr;
            const float bval = bias[col];
#pragma unroll
            for (int j = 0; j < 4; ++j) {
                const int row = r0 + wm * 64 + m * 16 + lg * 4 + j;
                const float v = acc[m][n][j] + bval;
                if (OUT_BF16)
                    ((bf16_t*)Cp)[(size_t)row * Ndim + col] = (bf16_t)v;
                else
                    ((float*)Cp)[(size_t)row * Ndim + col] = v;
            }
        }
    }
}

// ---------------------------------------------------------------------------
// Causal flash attention v3.
//  - one q-tile (64 rows) per block, 1024 blocks (4 blocks/CU, LDS=160KiB/CU)
//  - long blocks (qt=31) dispatched first
//  - Q pre-scaled by 0.125*log2e (folded into W_qkv/b_qkv)
//  - swapped QK^T, per-lane softmax, T13 defer-rescale (THR=8),
//    l-reduce deferred to epilogue, balanced max/sum trees
//  - K/V in XOR-swizzled LDS, double-buffered, T14 issue-early/write-late
// ---------------------------------------------------------------------------
__device__ __forceinline__ void st16s(bf16_t* base, int r, int c, float4 v) {
    const int byte = (r * 128 + c * 2) ^ ((r & 7) << 4);
    *(float4*)((char*)base + byte) = v;
}
__device__ __forceinline__ void st8s(bf16_t* base, int r, int c, bf16x4 v) {
    const int byte = (r * 128 + c * 2) ^ ((r & 7) << 4);
    *(bf16x4*)((char*)base + byte) = v;
}
__device__ __forceinline__ bf16x8 ld16s(const bf16_t* base, int r, int c) {
    const int byte = (r * 128 + c * 2) ^ ((r & 7) << 4);
    return *(const bf16x8*)((const char*)base + byte);
}

__global__ __launch_bounds__(256) void attn_kernel(
    const bf16_t* __restrict__ qkv, const bf16_t* __restrict__ vt,
    bf16_t* __restrict__ attn_out)
{
    __shared__ bf16_t Kl[2][64 * 64];
    __shared__ bf16_t Vl[2][64 * 64];
    __shared__ bf16_t Pl[4][16 * 64];
    const int bh = blockIdx.x & 31;
    const int qt = 31 - (blockIdx.x >> 5);     // long blocks first
    const int b = bh >> 4, h = bh & 15;
    const int q0 = qt << 6;
    const int t = threadIdx.x, lane = t & 63, wid = t >> 6;
    const int lr = lane & 15, lg = lane >> 4;
    const int sr = t >> 2, sc16 = (t & 3) << 4;

    const bf16_t* kbase = &qkv[(size_t)(b * SEQLEN) * N3 + EMB + h * 64];
    const bf16_t* vbase = &vt[(size_t)(bh * 64) * SEQLEN];

    auto ldK = [&](int kt, float4& a, float4& c) {
        const bf16_t* p = &kbase[(size_t)(kt * 64 + sr) * N3 + sc16];
        a = *(const float4*)p; c = *(const float4*)(p + 8);
    };
    auto ldV = [&](int kt, float4& a, float4& c) {
        const bf16_t* p = &vbase[(size_t)sr * SEQLEN + kt * 64 + sc16];
        a = *(const float4*)p; c = *(const float4*)(p + 8);
    };
    auto stKV = [&](int buf, float4 k0, float4 k1, float4 v0, float4 v1) {
        st16s(Kl[buf], sr, sc16, k0); st16s(Kl[buf], sr, sc16 + 8, k1);
        st16s(Vl[buf], sr, sc16, v0); st16s(Vl[buf], sr, sc16 + 8, v1);
    };

    const int qg = q0 + wid * 16 + lr;         // this lane's q row (S^T layout)
    bf16x8 qa0, qa1;
    {
        const bf16_t* qb = &qkv[(size_t)(b * SEQLEN + qg) * N3 + h * 64];
        qa0 = *(const bf16x8*)&qb[lg * 8];
        qa1 = *(const bf16x8*)&qb[32 + lg * 8];
    }
    f32x4 o[4] = {};
    float m_run = NEG_INF, l_run = 0.f;

    {   // prologue: stage kt=0 into buf 0
        float4 k0, k1, v0, v1;
        ldK(0, k0, k1); ldV(0, v0, v1);
        stKV(0, k0, k1, v0, v1);
    }
    __syncthreads();
    int cur = 0;
    for (int kt = 0; kt <= qt; ++kt) {
        // T14 issue-early: next tile's global loads
        float4 nk0, nk1, nv0, nv1;
        const bool more = (kt < qt);
        if (more) { ldK(kt + 1, nk0, nk1); ldV(kt + 1, nv0, nv1); }

        // QK^T (swapped): sc[n][j] = S[k = kt*64+16n+4*lg+j][q = qg], pre-scaled
        f32x4 sc[4] = {};
#pragma unroll
        for (int n = 0; n < 4; ++n) {
            bf16x8 kb0 = ld16s(Kl[cur], n * 16 + lr, lg * 8);
            bf16x8 kb1 = ld16s(Kl[cur], n * 16 + lr, 32 + lg * 8);
            sc[n] = __builtin_amdgcn_mfma_f32_16x16x32_bf16(kb0, qa0, sc[n], 0, 0, 0);
            sc[n] = __builtin_amdgcn_mfma_f32_16x16x32_bf16(kb1, qa1, sc[n], 0, 0, 0);
        }

        // causal mask on diagonal tile only
        if (kt == qt) {
#pragma unroll
            for (int n = 0; n < 4; ++n)
#pragma unroll
                for (int j = 0; j < 4; ++j) {
                    const int kg = kt * 64 + n * 16 + lg * 4 + j;
                    sc[n][j] = (kg <= qg) ? sc[n][j] : NEG_INF;
                }
        }
        // balanced row-max tree (max3-fusable)
        float mx[4];
#pragma unroll
        for (int n = 0; n < 4; ++n)
            mx[n] = fmaxf(fmaxf(sc[n][0], sc[n][1]), fmaxf(sc[n][2], sc[n][3]));
        float pmax = fmaxf(fmaxf(mx[0], mx[1]), fmaxf(mx[2], mx[3]));
        pmax = fmaxf(pmax, __shfl_xor(pmax, 16));
        pmax = fmaxf(pmax, __shfl_xor(pmax, 32));

        // T13 defer-rescale: only pay alpha path when max grew past THR=8
        if (__any(pmax > m_run + 8.f)) {
            const float mnew = fmaxf(m_run, pmax);
            const float alpha = exp2f(m_run - mnew);
            m_run = mnew;
            l_run *= alpha;
            float al[4];
#pragma unroll
            for (int j = 0; j < 4; ++j) al[j] = __shfl(alpha, lg * 4 + j);
#pragma unroll
            for (int dn = 0; dn < 4; ++dn)
#pragma unroll
                for (int j = 0; j < 4; ++j) o[dn][j] *= al[j];
        }

        // exp2 + per-lane partial sum (cross-lane reduce deferred to epilogue)
        float rs[4];
#pragma unroll
        for (int n = 0; n < 4; ++n) {
#pragma unroll
            for (int j = 0; j < 4; ++j) sc[n][j] = exp2f(sc[n][j] - m_run);
            rs[n] = (sc[n][0] + sc[n][1]) + (sc[n][2] + sc[n][3]);
        }
        l_run += (rs[0] + rs[1]) + (rs[2] + rs[3]);

        // P -> LDS [q][k], packed b64 (k-consecutive per lane)
#pragma unroll
        for (int n = 0; n < 4; ++n) {
            bf16x4 pk;
#pragma unroll
            for (int j = 0; j < 4; ++j) pk[j] = (bf16_t)sc[n][j];
            st8s(Pl[wid], lr, n * 16 + lg * 4, pk);
        }

        // PV: o[dn] (q = lg*4+j rows, d = dn*16+lr cols)
#pragma unroll
        for (int s2 = 0; s2 < 2; ++s2) {
            bf16x8 pa = ld16s(Pl[wid], lr, s2 * 32 + lg * 8);
#pragma unroll
            for (int dn = 0; dn < 4; ++dn) {
                bf16x8 vb = ld16s(Vl[cur], dn * 16 + lr, s2 * 32 + lg * 8);
                o[dn] = __builtin_amdgcn_mfma_f32_16x16x32_bf16(pa, vb, o[dn], 0, 0, 0);
            }
        }

        // write-late: commit next tile into the other buffer
        if (more) stKV(cur ^ 1, nk0, nk1, nv0, nv1);
        __syncthreads();
        cur ^= 1;
    }

    // epilogue: cross-lane l reduce, normalize, store
    float lt = l_run;
    lt += __shfl_xor(lt, 16);
    lt += __shfl_xor(lt, 32);
    float li[4];
#pragma unroll
    for (int j = 0; j < 4; ++j) li[j] = 1.0f / __shfl(lt, lg * 4 + j);
#pragma unroll
    for (int dn = 0; dn < 4; ++dn)
#pragma unroll
        for (int j = 0; j < 4; ++j) {
            const int row = b * SEQLEN + q0 + wid * 16 + lg * 4 + j;
            attn_out[(size_t)row * EMB + h * 64 + dn * 16 + lr] =
                (bf16_t)(o[dn][j] * li[j]);
        }
}

// ---------------------------------------------------------------------------
extern "C" void kernel_launch(void* const* d_in, const int* in_sizes, int n_in,
                              void* d_out, int out_size, void* d_ws, size_t ws_size,
                              hipStream_t stream)
{
    const float* X     = (const float*)d_in[0];
    const float* W_qkv = (const float*)d_in[1];
    const float* b_qkv = (const float*)d_in[2];
    const float* W_out = (const float*)d_in[3];
    const float* b_out = (const float*)d_in[4];
    float* out = (float*)d_out;

    char* ws = (char*)d_ws;
    bf16_t* Wqkv_t = (bf16_t*)ws;                           //  6 MB [3072][1024]
    bf16_t* Wout_t = (bf16_t*)(ws + 6u * 1024 * 1024);      //  2 MB [1024][1024]
    bf16_t* qkv    = (bf16_t*)(ws + 8u * 1024 * 1024);      // 24 MB [4096][3072]
    bf16_t* attn   = (bf16_t*)(ws + 32u * 1024 * 1024);     //  8 MB [4096][1024]
    bf16_t* Xb     = (bf16_t*)(ws + 40u * 1024 * 1024);     //  8 MB [4096][1024]
    bf16_t* Vt_g   = (bf16_t*)(ws + 48u * 1024 * 1024);     //  8 MB [32][64][2048]
    float*  bq_s   = (float*)(ws + 56u * 1024 * 1024);      // 12 KB scaled b_qkv

    dim3 blk(256);
    // Q columns (out-dim < 1024) pre-scaled by 0.125*log2e
    transpose_w_bf16<<<dim3(N3 / 64, EMB / 64), blk, 0, stream>>>(W_qkv, Wqkv_t, EMB, N3, EMB);
    transpose_w_bf16<<<dim3(EMB / 64, EMB / 64), blk, 0, stream>>>(W_out, Wout_t, EMB, EMB, 0);
    scale_bias<<<(N3 + 255) / 256, blk, 0, stream>>>(b_qkv, bq_s);
    cvt_f32_bf16<<<4096 * 1024 / (256 * 8), blk, 0, stream>>>(X, Xb, 4096 * 1024);

    // qkv = X @ W_qkv + b_qkv  (M=4096, N=3072, K=1024), bf16 out; grid 768 % 8 == 0
    gemm_bt_kernel<true><<<(4096 / 128) * (N3 / 128), blk, 0, stream>>>(
        Xb, Wqkv_t, bq_s, (void*)qkv, 4096, N3, EMB);

    // V extract+transpose -> [bh][64][2048]
    v_transpose<<<32 * (SEQLEN / 64), blk, 0, stream>>>(qkv, Vt_g);

    // causal flash attention -> attn [4096][1024] bf16
    attn_kernel<<<32 * 32, blk, 0, stream>>>(qkv, Vt_g, attn);

    // out = attn @ W_out + b_out  (M=4096, N=1024, K=1024), fp32 out; grid 256 % 8 == 0
    gemm_bt_kernel<false><<<(4096 / 128) * (EMB / 128), blk, 0, stream>>>(
        attn, Wout_t, b_out, (void*)out, 4096, EMB, EMB);
}

// Round 5
// 128.578 us; speedup vs baseline: 2.0807x; 1.0343x over previous
//
#include <hip/hip_runtime.h>

typedef __bf16 bf16_t;
typedef bf16_t bf16x8 __attribute__((ext_vector_type(8)));
typedef bf16_t bf16x4 __attribute__((ext_vector_type(4)));
typedef float f32x4 __attribute__((ext_vector_type(4)));

#define SEQLEN 2048
#define EMB 1024
#define NHEADS 16
#define N3 3072
#define NBATCH 2
#define NEG_INF (-__builtin_inff())
#define SC2 0.18033688011112042f   // 0.125 * log2(e): softmax in exp2 domain

// async global->LDS, 16B per lane. LDS base must be wave-uniform.
__device__ __forceinline__ void async16(bf16_t* lds, const bf16_t* g) {
    __builtin_amdgcn_global_load_lds(
        (const __attribute__((address_space(1))) void*)g,
        (__attribute__((address_space(3))) void*)lds, 16, 0, 0);
}

// ---------------------------------------------------------------------------
// Transpose + fp32->bf16 convert: W [K][N] fp32 -> Wt [N][K] bf16.
// Rows n < scale_below are multiplied by SC2 (pre-scaled Q path).
// ---------------------------------------------------------------------------
__global__ __launch_bounds__(256) void transpose_w_bf16(
    const float* __restrict__ W, bf16_t* __restrict__ Wt, int K, int N,
    int scale_below)
{
    __shared__ float tile[64][65];
    const int n0 = blockIdx.x * 64, k0 = blockIdx.y * 64;
    const float s = (n0 < scale_below) ? SC2 : 1.0f;
    const int t = threadIdx.x;
    const int nl = t & 63, k4 = t >> 6;
#pragma unroll
    for (int i = 0; i < 16; ++i) {
        int kk = k4 + i * 4;
        tile[kk][nl] = W[(size_t)(k0 + kk) * N + n0 + nl];
    }
    __syncthreads();
    const int kl = t & 63, n4 = t >> 6;
#pragma unroll
    for (int i = 0; i < 16; ++i) {
        int nn = n4 + i * 4;
        Wt[(size_t)(n0 + nn) * K + k0 + kl] = (bf16_t)(tile[kl][nn] * s);
    }
}

__global__ __launch_bounds__(256) void scale_bias(
    const float* __restrict__ b, float* __restrict__ out)
{
    const int i = blockIdx.x * 256 + threadIdx.x;
    if (i < N3) out[i] = b[i] * (i < EMB ? SC2 : 1.0f);
}

// ---------------------------------------------------------------------------
// fp32 -> bf16 convert (X pre-convert), 8 elems/thread
// ---------------------------------------------------------------------------
__global__ __launch_bounds__(256) void cvt_f32_bf16(
    const float* __restrict__ in, bf16_t* __restrict__ out, int n)
{
    const int i = (blockIdx.x * 256 + threadIdx.x) * 8;
    if (i >= n) return;
    float4 a = *(const float4*)&in[i];
    float4 b = *(const float4*)&in[i + 4];
    bf16_t v[8];
    v[0] = (bf16_t)a.x; v[1] = (bf16_t)a.y; v[2] = (bf16_t)a.z; v[3] = (bf16_t)a.w;
    v[4] = (bf16_t)b.x; v[5] = (bf16_t)b.y; v[6] = (bf16_t)b.z; v[7] = (bf16_t)b.w;
    *(float4*)&out[i] = *(float4*)&v[0];
}

// ---------------------------------------------------------------------------
// Extract V from qkv and transpose: vt[bh][d=64][s=2048]
// ---------------------------------------------------------------------------
__global__ __launch_bounds__(256) void v_transpose(
    const bf16_t* __restrict__ qkv, bf16_t* __restrict__ vt)
{
    __shared__ bf16_t tile[64][72];
    const int bh = blockIdx.x & 31, st = blockIdx.x >> 5;
    const int b = bh >> 4, h = bh & 15;
    const int t = threadIdx.x;
    const int sr = t >> 2, dc = (t & 3) << 4;
    const bf16_t* src = &qkv[(size_t)(b * SEQLEN + st * 64 + sr) * N3 + 2 * EMB + h * 64 + dc];
    *(float4*)&tile[sr][dc]     = *(const float4*)src;
    *(float4*)&tile[sr][dc + 8] = *(const float4*)(src + 8);
    __syncthreads();
    const int d = t >> 2, scol = (t & 3) << 4;
    bf16_t v[16];
#pragma unroll
    for (int i = 0; i < 16; ++i) v[i] = tile[scol + i][d];
    bf16_t* dst = &vt[(size_t)(bh * 64 + d) * SEQLEN + st * 64 + scol];
    *(float4*)&dst[0] = *(float4*)&v[0];
    *(float4*)&dst[8] = *(float4*)&v[8];
}

// ---------------------------------------------------------------------------
// GEMM (m97 structure): C[M][N] = A[M][K](bf16) @ Bt[N][K]^T + bias.
// ---------------------------------------------------------------------------
template<bool OUT_BF16>
__global__ __launch_bounds__(256) void gemm_bt_kernel(
    const bf16_t* __restrict__ A, const bf16_t* __restrict__ Bt,
    const float* __restrict__ bias, void* __restrict__ Cp,
    int Mdim, int Ndim, int Kdim)
{
    __shared__ bf16_t As[128 * 32];
    __shared__ bf16_t Bs[128 * 32];
    const int nb = Ndim >> 7;
    const int cpx = gridDim.x >> 3;
    const int bid = (blockIdx.x & 7) * cpx + (blockIdx.x >> 3);
    const int bx = bid % nb, by = bid / nb;
    const int r0 = by << 7, c0 = bx << 7;
    const int t = threadIdx.x, lane = t & 63;
    const int wid = t >> 6;
    const int wm = wid >> 1, wn = wid & 1;
    const int lr = lane & 15, lg = lane >> 4;

    const int glrow = wid * 32 + (lane >> 2);
    const int glcol = (lane & 3) << 3;
    bf16_t* ldsA = &As[wid * 1024];
    bf16_t* ldsB = &Bs[wid * 1024];
    const bf16_t* gA = &A[(size_t)(r0 + glrow) * Kdim + glcol];
    const bf16_t* gB = &Bt[(size_t)(c0 + glrow) * Kdim + glcol];
    const size_t rowstep = (size_t)16 * Kdim;

    f32x4 acc[4][4] = {};
    const int KT = Kdim >> 5;
    for (int kt = 0; kt < KT; ++kt) {
        const int k0 = kt << 5;
        async16(ldsA,       gA + k0);
        async16(ldsA + 512, gA + k0 + rowstep);
        async16(ldsB,       gB + k0);
        async16(ldsB + 512, gB + k0 + rowstep);
        __syncthreads();
        bf16x8 af[4], bfm[4];
#pragma unroll
        for (int m = 0; m < 4; ++m)
            af[m] = *(const bf16x8*)&As[(wm * 64 + m * 16 + lr) * 32 + lg * 8];
#pragma unroll
        for (int n = 0; n < 4; ++n)
            bfm[n] = *(const bf16x8*)&Bs[(wn * 64 + n * 16 + lr) * 32 + lg * 8];
#pragma unroll
        for (int m = 0; m < 4; ++m)
#pragma unroll
            for (int n = 0; n < 4; ++n)
                acc[m][n] = __builtin_amdgcn_mfma_f32_16x16x32_bf16(
                    af[m], bfm[n], acc[m][n], 0, 0, 0);
        __syncthreads();
    }

#pragma unroll
    for (int m = 0; m < 4; ++m) {
#pragma unroll
        for (int n = 0; n < 4; ++n) {
            const int col = c0 + wn * 64 + n * 16 + lr;
            const float bval = bias[col];
#pragma unroll
            for (int j = 0; j < 4; ++j) {
                const int row = r0 + wm * 64 + m * 16 + lg * 4 + j;
                const float v = acc[m][n][j] + bval;
                if (OUT_BF16)
                    ((bf16_t*)Cp)[(size_t)row * Ndim + col] = (bf16_t)v;
                else
                    ((float*)Cp)[(size_t)row * Ndim + col] = v;
            }
        }
    }
}

// ---------------------------------------------------------------------------
// Causal flash attention v4b (v4 + swizzle-offset fix).
//  - FIX: second-half fragment base computed as (addr+64)^swz, NOT (addr^swz)+64
//    (swizzle mask occupies bits 4-6; adding 64 after XOR carries into bit 7).
//  - balanced (qt,bh) dispatch; T12 in-register P via cvt_pk+permlane32_swap
//    (kappa = swap bits 2<->3, matched by V quad shuffle at stage time);
//  - pmax cross-lane reduce only inside rare T13 branch; K/V XOR-swizzled
//    double-buffered LDS; T14 issue-early/write-late; T5 setprio.
// ---------------------------------------------------------------------------
__global__ __launch_bounds__(256, 4) void attn_kernel(
    const bf16_t* __restrict__ qkv, const bf16_t* __restrict__ vt,
    bf16_t* __restrict__ attn_out)
{
    __shared__ bf16_t Kl[2][4096];
    __shared__ bf16_t Vl[2][4096];
    const int d = blockIdx.x;
    const int r = d >> 8;                 // resident round
    const int u = (d >> 3) & 31;
    int qt = (r & 1) ? (31 - u) : u;
    if (r & 2) qt ^= 16;
    const int bh = (d & 7) + (r << 3);
    const int b = bh >> 4, h = bh & 15;
    const int q0 = qt << 6;
    const int t = threadIdx.x, lane = t & 63, wid = t >> 6;
    const int lr = lane & 15, lg = lane >> 4;
    const int sr = t >> 2, sc16 = (t & 3) << 4;

    // lane-constant LDS byte offsets; XOR applied AFTER all sub-bit-7 adds
    const int fragb0 = (lr * 128 + lg * 16) ^ ((lr & 7) << 4);
    const int fragb1 = (lr * 128 + 64 + lg * 16) ^ ((lr & 7) << 4);
    const int stb0   = (sr * 128 + sc16 * 2) ^ ((sr & 7) << 4);
    const int stb1   = (sr * 128 + sc16 * 2 + 16) ^ ((sr & 7) << 4);

    // running global pointers for staging
    const bf16_t* kp = &qkv[(size_t)(b * SEQLEN + sr) * N3 + EMB + h * 64 + sc16];
    const bf16_t* vp = &vt[(size_t)(bh * 64 + sr) * SEQLEN + sc16];
    const size_t kstep = (size_t)64 * N3;

    const int qg = q0 + wid * 16 + lr;    // this lane's q row (S^T layout)
    bf16x8 qa0, qa1;
    {
        const bf16_t* qb = &qkv[(size_t)(b * SEQLEN + qg) * N3 + h * 64];
        qa0 = *(const bf16x8*)&qb[lg * 8];
        qa1 = *(const bf16x8*)&qb[32 + lg * 8];
    }
    f32x4 o[4] = {};
    float m_run = NEG_INF, l_run = 0.f;

    auto stK = [&](char* base, float4 a, float4 c) {
        *(float4*)(base + stb0) = a; *(float4*)(base + stb1) = c;
    };
    auto stV = [&](char* base, float4 a, float4 c) {
        // quad shuffle phi = kappa^-1 within each 16: (A0,A1,C0,C1)->(A0,C0|A1,C1)
        float4 w0 = {a.x, a.y, c.x, c.y};
        float4 w1 = {a.z, a.w, c.z, c.w};
        *(float4*)(base + stb0) = w0; *(float4*)(base + stb1) = w1;
    };

    {   // prologue: stage kt=0 into buf 0
        float4 k0 = *(const float4*)kp, k1 = *(const float4*)(kp + 8);
        float4 v0 = *(const float4*)vp, v1 = *(const float4*)(vp + 8);
        stK((char*)Kl[0], k0, k1);
        stV((char*)Vl[0], v0, v1);
    }
    __syncthreads();
    int cur = 0;
    for (int kt = 0; kt <= qt; ++kt) {
        // T14 issue-early: next tile's global loads
        float4 nk0, nk1, nv0, nv1;
        const bool more = (kt < qt);
        if (more) {
            kp += kstep; vp += 64;
            nk0 = *(const float4*)kp; nk1 = *(const float4*)(kp + 8);
            nv0 = *(const float4*)vp; nv1 = *(const float4*)(vp + 8);
        }

        const char* Kc = (const char*)Kl[cur];
        const char* Vc = (const char*)Vl[cur];

        // QK^T (swapped): sc[n][j] = S^T[k = kt*64+16n+4lg+j][q = qg]
        f32x4 sc[4] = {};
        __builtin_amdgcn_s_setprio(1);
#pragma unroll
        for (int n = 0; n < 4; ++n) {
            bf16x8 kb0 = *(const bf16x8*)(Kc + (fragb0 + n * 2048));
            bf16x8 kb1 = *(const bf16x8*)(Kc + (fragb1 + n * 2048));
            sc[n] = __builtin_amdgcn_mfma_f32_16x16x32_bf16(kb0, qa0, sc[n], 0, 0, 0);
            sc[n] = __builtin_amdgcn_mfma_f32_16x16x32_bf16(kb1, qa1, sc[n], 0, 0, 0);
        }
        __builtin_amdgcn_s_setprio(0);

        // causal mask on diagonal tile only
        if (kt == qt) {
#pragma unroll
            for (int n = 0; n < 4; ++n)
#pragma unroll
                for (int j = 0; j < 4; ++j) {
                    const int kg = kt * 64 + n * 16 + lg * 4 + j;
                    sc[n][j] = (kg <= qg) ? sc[n][j] : NEG_INF;
                }
        }
        // per-lane max (no cross-lane in common path)
        float mx[4];
#pragma unroll
        for (int n = 0; n < 4; ++n)
            mx[n] = fmaxf(fmaxf(fmaxf(sc[n][0], sc[n][1]), sc[n][2]), sc[n][3]);
        float pmax = fmaxf(fmaxf(fmaxf(mx[0], mx[1]), mx[2]), mx[3]);

        // T13 defer-rescale: rare branch does the full reduce + update
        if (__any(pmax > m_run + 8.f)) {
            float pm = fmaxf(pmax, __shfl_xor(pmax, 16));
            pm = fmaxf(pm, __shfl_xor(pm, 32));
            const float mnew = fmaxf(m_run, pm);
            const float alpha = exp2f(m_run - mnew);
            m_run = mnew;
            l_run *= alpha;
            float al[4];
#pragma unroll
            for (int j = 0; j < 4; ++j) al[j] = __shfl(alpha, lg * 4 + j);
#pragma unroll
            for (int dn = 0; dn < 4; ++dn)
#pragma unroll
                for (int j = 0; j < 4; ++j) o[dn][j] *= al[j];
        }

        // exp2 + per-lane partial sum (cross-lane reduce deferred to epilogue)
        float rs[4];
#pragma unroll
        for (int n = 0; n < 4; ++n) {
#pragma unroll
            for (int j = 0; j < 4; ++j) sc[n][j] = exp2f(sc[n][j] - m_run);
            rs[n] = (sc[n][0] + sc[n][1]) + (sc[n][2] + sc[n][3]);
        }
        l_run += (rs[0] + rs[1]) + (rs[2] + rs[3]);

        // T12: P -> bf16 pairs, permlane32_swap (DST upper <-> SRC lower)
        unsigned pk00, pk01, pk10, pk11, pk20, pk21, pk30, pk31;
        asm("v_cvt_pk_bf16_f32 %0, %1, %2" : "=v"(pk00) : "v"(sc[0][0]), "v"(sc[0][1]));
        asm("v_cvt_pk_bf16_f32 %0, %1, %2" : "=v"(pk01) : "v"(sc[0][2]), "v"(sc[0][3]));
        asm("v_cvt_pk_bf16_f32 %0, %1, %2" : "=v"(pk10) : "v"(sc[1][0]), "v"(sc[1][1]));
        asm("v_cvt_pk_bf16_f32 %0, %1, %2" : "=v"(pk11) : "v"(sc[1][2]), "v"(sc[1][3]));
        asm("v_cvt_pk_bf16_f32 %0, %1, %2" : "=v"(pk20) : "v"(sc[2][0]), "v"(sc[2][1]));
        asm("v_cvt_pk_bf16_f32 %0, %1, %2" : "=v"(pk21) : "v"(sc[2][2]), "v"(sc[2][3]));
        asm("v_cvt_pk_bf16_f32 %0, %1, %2" : "=v"(pk30) : "v"(sc[3][0]), "v"(sc[3][1]));
        asm("v_cvt_pk_bf16_f32 %0, %1, %2" : "=v"(pk31) : "v"(sc[3][2]), "v"(sc[3][3]));
        asm("v_permlane32_swap_b32 %0, %1" : "+v"(pk00), "+v"(pk10));
        asm("v_permlane32_swap_b32 %0, %1" : "+v"(pk01), "+v"(pk11));
        asm("v_permlane32_swap_b32 %0, %1" : "+v"(pk20), "+v"(pk30));
        asm("v_permlane32_swap_b32 %0, %1" : "+v"(pk21), "+v"(pk31));
        union UW { unsigned w[4]; bf16x8 v; };
        UW ua, ub;
        ua.w[0] = pk00; ua.w[1] = pk01; ua.w[2] = pk10; ua.w[3] = pk11;
        ub.w[0] = pk20; ub.w[1] = pk21; ub.w[2] = pk30; ub.w[3] = pk31;
        const bf16x8 pa0 = ua.v, pa1 = ub.v;

        // PV: o[dn] += P[q][kappa] * V[kappa][d]
        __builtin_amdgcn_s_setprio(1);
#pragma unroll
        for (int dn = 0; dn < 4; ++dn) {
            bf16x8 vb0 = *(const bf16x8*)(Vc + (fragb0 + dn * 2048));
            bf16x8 vb1 = *(const bf16x8*)(Vc + (fragb1 + dn * 2048));
            o[dn] = __builtin_amdgcn_mfma_f32_16x16x32_bf16(pa0, vb0, o[dn], 0, 0, 0);
            o[dn] = __builtin_amdgcn_mfma_f32_16x16x32_bf16(pa1, vb1, o[dn], 0, 0, 0);
        }
        __builtin_amdgcn_s_setprio(0);

        // write-late: commit next tile into the other buffer
        if (more) {
            stK((char*)Kl[cur ^ 1], nk0, nk1);
            stV((char*)Vl[cur ^ 1], nv0, nv1);
        }
        __syncthreads();
        cur ^= 1;
    }

    // epilogue: cross-lane l reduce, normalize, store
    float lt = l_run;
    lt += __shfl_xor(lt, 16);
    lt += __shfl_xor(lt, 32);
    float li[4];
#pragma unroll
    for (int j = 0; j < 4; ++j) li[j] = 1.0f / __shfl(lt, lg * 4 + j);
#pragma unroll
    for (int dn = 0; dn < 4; ++dn)
#pragma unroll
        for (int j = 0; j < 4; ++j) {
            const int row = b * SEQLEN + q0 + wid * 16 + lg * 4 + j;
            attn_out[(size_t)row * EMB + h * 64 + dn * 16 + lr] =
                (bf16_t)(o[dn][j] * li[j]);
        }
}

// ---------------------------------------------------------------------------
extern "C" void kernel_launch(void* const* d_in, const int* in_sizes, int n_in,
                              void* d_out, int out_size, void* d_ws, size_t ws_size,
                              hipStream_t stream)
{
    const float* X     = (const float*)d_in[0];
    const float* W_qkv = (const float*)d_in[1];
    const float* b_qkv = (const float*)d_in[2];
    const float* W_out = (const float*)d_in[3];
    const float* b_out = (const float*)d_in[4];
    float* out = (float*)d_out;

    char* ws = (char*)d_ws;
    bf16_t* Wqkv_t = (bf16_t*)ws;                           //  6 MB [3072][1024]
    bf16_t* Wout_t = (bf16_t*)(ws + 6u * 1024 * 1024);      //  2 MB [1024][1024]
    bf16_t* qkv    = (bf16_t*)(ws + 8u * 1024 * 1024);      // 24 MB [4096][3072]
    bf16_t* attn   = (bf16_t*)(ws + 32u * 1024 * 1024);     //  8 MB [4096][1024]
    bf16_t* Xb     = (bf16_t*)(ws + 40u * 1024 * 1024);     //  8 MB [4096][1024]
    bf16_t* Vt_g   = (bf16_t*)(ws + 48u * 1024 * 1024);     //  8 MB [32][64][2048]
    float*  bq_s   = (float*)(ws + 56u * 1024 * 1024);      // 12 KB scaled b_qkv

    dim3 blk(256);
    transpose_w_bf16<<<dim3(N3 / 64, EMB / 64), blk, 0, stream>>>(W_qkv, Wqkv_t, EMB, N3, EMB);
    transpose_w_bf16<<<dim3(EMB / 64, EMB / 64), blk, 0, stream>>>(W_out, Wout_t, EMB, EMB, 0);
    scale_bias<<<(N3 + 255) / 256, blk, 0, stream>>>(b_qkv, bq_s);
    cvt_f32_bf16<<<4096 * 1024 / (256 * 8), blk, 0, stream>>>(X, Xb, 4096 * 1024);

    gemm_bt_kernel<true><<<(4096 / 128) * (N3 / 128), blk, 0, stream>>>(
        Xb, Wqkv_t, bq_s, (void*)qkv, 4096, N3, EMB);

    v_transpose<<<32 * (SEQLEN / 64), blk, 0, stream>>>(qkv, Vt_g);

    attn_kernel<<<32 * 32, blk, 0, stream>>>(qkv, Vt_g, attn);

    gemm_bt_kernel<false><<<(4096 / 128) * (EMB / 128), blk, 0, stream>>>(
        attn, Wout_t, b_out, (void*)out, 4096, EMB, EMB);
}

// Round 6
// 119.024 us; speedup vs baseline: 2.2477x; 1.0803x over previous
//
#include <hip/hip_runtime.h>

typedef __bf16 bf16_t;
typedef bf16_t bf16x8 __attribute__((ext_vector_type(8)));
typedef bf16_t bf16x4 __attribute__((ext_vector_type(4)));
typedef float f32x4 __attribute__((ext_vector_type(4)));

#define SEQLEN 2048
#define EMB 1024
#define NHEADS 16
#define N3 3072
#define NBATCH 2
#define NEG_INF (-__builtin_inff())
#define SC2 0.18033688011112042f   // 0.125 * log2(e): softmax in exp2 domain

// async global->LDS, 16B per lane. LDS base must be wave-uniform.
__device__ __forceinline__ void async16(bf16_t* lds, const bf16_t* g) {
    __builtin_amdgcn_global_load_lds(
        (const __attribute__((address_space(1))) void*)g,
        (__attribute__((address_space(3))) void*)lds, 16, 0, 0);
}

// ---------------------------------------------------------------------------
// Combined weight transpose + fp32->bf16: W_qkv (48 col-blocks, Q cols
// pre-scaled by SC2) and W_out (16 col-blocks) in one launch.
// ---------------------------------------------------------------------------
__global__ __launch_bounds__(256) void transpose_weights(
    const float* __restrict__ Wqkv, const float* __restrict__ Wout,
    bf16_t* __restrict__ Wqkv_t, bf16_t* __restrict__ Wout_t)
{
    __shared__ float tile[64][65];
    int bx = blockIdx.x;
    const int k0 = blockIdx.y * 64;
    const float* W; bf16_t* Wt; int N; float s;
    if (bx < 48) { W = Wqkv; Wt = Wqkv_t; N = N3;  s = (bx * 64 < EMB) ? SC2 : 1.0f; }
    else         { bx -= 48; W = Wout; Wt = Wout_t; N = EMB; s = 1.0f; }
    const int n0 = bx * 64;
    const int t = threadIdx.x;
    const int nl = t & 63, k4 = t >> 6;
#pragma unroll
    for (int i = 0; i < 16; ++i) {
        int kk = k4 + i * 4;
        tile[kk][nl] = W[(size_t)(k0 + kk) * N + n0 + nl];
    }
    __syncthreads();
    const int kl = t & 63, n4 = t >> 6;
#pragma unroll
    for (int i = 0; i < 16; ++i) {
        int nn = n4 + i * 4;
        Wt[(size_t)(n0 + nn) * EMB + k0 + kl] = (bf16_t)(tile[kl][nn] * s);
    }
}

// ---------------------------------------------------------------------------
// fp32 -> bf16 convert (X pre-convert), 8 elems/thread
// ---------------------------------------------------------------------------
__global__ __launch_bounds__(256) void cvt_f32_bf16(
    const float* __restrict__ in, bf16_t* __restrict__ out, int n)
{
    const int i = (blockIdx.x * 256 + threadIdx.x) * 8;
    if (i >= n) return;
    float4 a = *(const float4*)&in[i];
    float4 b = *(const float4*)&in[i + 4];
    bf16_t v[8];
    v[0] = (bf16_t)a.x; v[1] = (bf16_t)a.y; v[2] = (bf16_t)a.z; v[3] = (bf16_t)a.w;
    v[4] = (bf16_t)b.x; v[5] = (bf16_t)b.y; v[6] = (bf16_t)b.z; v[7] = (bf16_t)b.w;
    *(float4*)&out[i] = *(float4*)&v[0];
}

// ---------------------------------------------------------------------------
// GEMM (m97 structure): C[M][N] = A[M][K](bf16) @ Bt[N][K]^T + bias.
// V_SPLIT (GEMM1): col-blocks >= 2048 write transposed into vt[bh][d][s]
// instead of qkv (C-frag j=0..3 are 4 consecutive s -> native 8B stores).
// scale_q: bias cols < EMB multiplied by SC2 (replaces scale_bias kernel).
// ---------------------------------------------------------------------------
template<bool OUT_BF16, bool V_SPLIT>
__global__ __launch_bounds__(256) void gemm_bt_kernel(
    const bf16_t* __restrict__ A, const bf16_t* __restrict__ Bt,
    const float* __restrict__ bias, void* __restrict__ Cp,
    bf16_t* __restrict__ vt, int scale_q,
    int Mdim, int Ndim, int Kdim)
{
    __shared__ bf16_t As[128 * 32];
    __shared__ bf16_t Bs[128 * 32];
    const int nb = Ndim >> 7;
    const int cpx = gridDim.x >> 3;
    const int bid = (blockIdx.x & 7) * cpx + (blockIdx.x >> 3);
    const int bx = bid % nb, by = bid / nb;
    const int r0 = by << 7, c0 = bx << 7;
    const int t = threadIdx.x, lane = t & 63;
    const int wid = t >> 6;
    const int wm = wid >> 1, wn = wid & 1;
    const int lr = lane & 15, lg = lane >> 4;

    const int glrow = wid * 32 + (lane >> 2);
    const int glcol = (lane & 3) << 3;
    bf16_t* ldsA = &As[wid * 1024];
    bf16_t* ldsB = &Bs[wid * 1024];
    const bf16_t* gA = &A[(size_t)(r0 + glrow) * Kdim + glcol];
    const bf16_t* gB = &Bt[(size_t)(c0 + glrow) * Kdim + glcol];
    const size_t rowstep = (size_t)16 * Kdim;

    f32x4 acc[4][4] = {};
    const int KT = Kdim >> 5;
    for (int kt = 0; kt < KT; ++kt) {
        const int k0 = kt << 5;
        async16(ldsA,       gA + k0);
        async16(ldsA + 512, gA + k0 + rowstep);
        async16(ldsB,       gB + k0);
        async16(ldsB + 512, gB + k0 + rowstep);
        __syncthreads();
        bf16x8 af[4], bfm[4];
#pragma unroll
        for (int m = 0; m < 4; ++m)
            af[m] = *(const bf16x8*)&As[(wm * 64 + m * 16 + lr) * 32 + lg * 8];
#pragma unroll
        for (int n = 0; n < 4; ++n)
            bfm[n] = *(const bf16x8*)&Bs[(wn * 64 + n * 16 + lr) * 32 + lg * 8];
#pragma unroll
        for (int m = 0; m < 4; ++m)
#pragma unroll
            for (int n = 0; n < 4; ++n)
                acc[m][n] = __builtin_amdgcn_mfma_f32_16x16x32_bf16(
                    af[m], bfm[n], acc[m][n], 0, 0, 0);
        __syncthreads();
    }

    const bool vmode = V_SPLIT && (c0 >= 2 * EMB);
#pragma unroll
    for (int m = 0; m < 4; ++m) {
#pragma unroll
        for (int n = 0; n < 4; ++n) {
            const int col = c0 + wn * 64 + n * 16 + lr;
            float bval = bias[col];
            if (scale_q && col < EMB) bval *= SC2;
            if (vmode) {
                const int h = (col - 2 * EMB) >> 6, dd = col & 63;
                const int bb = r0 >> 11;
                const int sbase = (r0 & (SEQLEN - 1)) + wm * 64 + m * 16 + lg * 4;
                bf16x4 pk;
#pragma unroll
                for (int j = 0; j < 4; ++j) pk[j] = (bf16_t)(acc[m][n][j] + bval);
                *(bf16x4*)&vt[(size_t)((bb * 16 + h) * 64 + dd) * SEQLEN + sbase] = pk;
            } else {
#pragma unroll
                for (int j = 0; j < 4; ++j) {
                    const int row = r0 + wm * 64 + m * 16 + lg * 4 + j;
                    const float v = acc[m][n][j] + bval;
                    if (OUT_BF16)
                        ((bf16_t*)Cp)[(size_t)row * Ndim + col] = (bf16_t)v;
                    else
                        ((float*)Cp)[(size_t)row * Ndim + col] = v;
                }
            }
        }
    }
}

// ---------------------------------------------------------------------------
// Causal flash attention v5 (v4b + MFMA ones-column row-sum).
//  - l computed as a 5th PV accumulator against a constant all-ones B-frag:
//    every lane holds its q-row's sum in C-layout -> no fp32 sum chain, no
//    epilogue shuffles, rescale fully aligned with o.
//  - balanced (qt,bh) dispatch; T12 in-register P (cvt_pk + permlane32_swap,
//    kappa = swap bits 2<->3, matched by V quad shuffle at stage time);
//  - K/V XOR-swizzled double-buffered LDS; T14 issue-early/write-late; T5.
// ---------------------------------------------------------------------------
__global__ __launch_bounds__(256, 4) void attn_kernel(
    const bf16_t* __restrict__ qkv, const bf16_t* __restrict__ vt,
    bf16_t* __restrict__ attn_out)
{
    __shared__ bf16_t Kl[2][4096];
    __shared__ bf16_t Vl[2][4096];
    const int d = blockIdx.x;
    const int r = d >> 8;                 // resident round
    const int u = (d >> 3) & 31;
    int qt = (r & 1) ? (31 - u) : u;
    if (r & 2) qt ^= 16;
    const int bh = (d & 7) + (r << 3);
    const int b = bh >> 4, h = bh & 15;
    const int q0 = qt << 6;
    const int t = threadIdx.x, lane = t & 63, wid = t >> 6;
    const int lr = lane & 15, lg = lane >> 4;
    const int sr = t >> 2, sc16 = (t & 3) << 4;

    // lane-constant LDS byte offsets; XOR applied AFTER all sub-bit-7 adds
    const int fragb0 = (lr * 128 + lg * 16) ^ ((lr & 7) << 4);
    const int fragb1 = (lr * 128 + 64 + lg * 16) ^ ((lr & 7) << 4);
    const int stb0   = (sr * 128 + sc16 * 2) ^ ((sr & 7) << 4);
    const int stb1   = (sr * 128 + sc16 * 2 + 16) ^ ((sr & 7) << 4);

    // running global pointers for staging
    const bf16_t* kp = &qkv[(size_t)(b * SEQLEN + sr) * N3 + EMB + h * 64 + sc16];
    const bf16_t* vp = &vt[(size_t)(bh * 64 + sr) * SEQLEN + sc16];
    const size_t kstep = (size_t)64 * N3;

    const int qg = q0 + wid * 16 + lr;    // this lane's q row (S^T layout)
    bf16x8 qa0, qa1;
    {
        const bf16_t* qb = &qkv[(size_t)(b * SEQLEN + qg) * N3 + h * 64];
        qa0 = *(const bf16x8*)&qb[lg * 8];
        qa1 = *(const bf16x8*)&qb[32 + lg * 8];
    }
    bf16x8 ones;
#pragma unroll
    for (int i = 0; i < 8; ++i) ones[i] = (bf16_t)1.0f;

    f32x4 o[4] = {};
    f32x4 ol = {};                        // row-sum accumulator (ones column)
    float m_run = NEG_INF;

    auto stK = [&](char* base, float4 a, float4 c) {
        *(float4*)(base + stb0) = a; *(float4*)(base + stb1) = c;
    };
    auto stV = [&](char* base, float4 a, float4 c) {
        // quad shuffle phi = kappa^-1 within each 16: (A0,A1,C0,C1)->(A0,C0|A1,C1)
        float4 w0 = {a.x, a.y, c.x, c.y};
        float4 w1 = {a.z, a.w, c.z, c.w};
        *(float4*)(base + stb0) = w0; *(float4*)(base + stb1) = w1;
    };

    {   // prologue: stage kt=0 into buf 0
        float4 k0 = *(const float4*)kp, k1 = *(const float4*)(kp + 8);
        float4 v0 = *(const float4*)vp, v1 = *(const float4*)(vp + 8);
        stK((char*)Kl[0], k0, k1);
        stV((char*)Vl[0], v0, v1);
    }
    __syncthreads();
    int cur = 0;
    for (int kt = 0; kt <= qt; ++kt) {
        // T14 issue-early: next tile's global loads
        float4 nk0, nk1, nv0, nv1;
        const bool more = (kt < qt);
        if (more) {
            kp += kstep; vp += 64;
            nk0 = *(const float4*)kp; nk1 = *(const float4*)(kp + 8);
            nv0 = *(const float4*)vp; nv1 = *(const float4*)(vp + 8);
        }

        const char* Kc = (const char*)Kl[cur];
        const char* Vc = (const char*)Vl[cur];

        // QK^T (swapped): sc[n][j] = S^T[k = kt*64+16n+4lg+j][q = qg]
        f32x4 sc[4] = {};
        __builtin_amdgcn_s_setprio(1);
#pragma unroll
        for (int n = 0; n < 4; ++n) {
            bf16x8 kb0 = *(const bf16x8*)(Kc + (fragb0 + n * 2048));
            bf16x8 kb1 = *(const bf16x8*)(Kc + (fragb1 + n * 2048));
            sc[n] = __builtin_amdgcn_mfma_f32_16x16x32_bf16(kb0, qa0, sc[n], 0, 0, 0);
            sc[n] = __builtin_amdgcn_mfma_f32_16x16x32_bf16(kb1, qa1, sc[n], 0, 0, 0);
        }
        __builtin_amdgcn_s_setprio(0);

        // causal mask on diagonal tile only
        if (kt == qt) {
#pragma unroll
            for (int n = 0; n < 4; ++n)
#pragma unroll
                for (int j = 0; j < 4; ++j) {
                    const int kg = kt * 64 + n * 16 + lg * 4 + j;
                    sc[n][j] = (kg <= qg) ? sc[n][j] : NEG_INF;
                }
        }
        // per-lane max (no cross-lane in common path)
        float mx[4];
#pragma unroll
        for (int n = 0; n < 4; ++n)
            mx[n] = fmaxf(fmaxf(fmaxf(sc[n][0], sc[n][1]), sc[n][2]), sc[n][3]);
        float pmax = fmaxf(fmaxf(fmaxf(mx[0], mx[1]), mx[2]), mx[3]);

        // T13 defer-rescale: rare branch does the full reduce + update
        if (__any(pmax > m_run + 8.f)) {
            float pm = fmaxf(pmax, __shfl_xor(pmax, 16));
            pm = fmaxf(pm, __shfl_xor(pm, 32));
            const float mnew = fmaxf(m_run, pm);
            const float alpha = exp2f(m_run - mnew);
            m_run = mnew;
            float al[4];
#pragma unroll
            for (int j = 0; j < 4; ++j) al[j] = __shfl(alpha, lg * 4 + j);
#pragma unroll
            for (int dn = 0; dn < 4; ++dn)
#pragma unroll
                for (int j = 0; j < 4; ++j) o[dn][j] *= al[j];
#pragma unroll
            for (int j = 0; j < 4; ++j) ol[j] *= al[j];
        }

        // exp2 (per-lane; row-sum comes from the ones-column MFMA)
#pragma unroll
        for (int n = 0; n < 4; ++n)
#pragma unroll
            for (int j = 0; j < 4; ++j) sc[n][j] = exp2f(sc[n][j] - m_run);

        // T12: P -> bf16 pairs, permlane32_swap (DST upper <-> SRC lower)
        unsigned pk00, pk01, pk10, pk11, pk20, pk21, pk30, pk31;
        asm("v_cvt_pk_bf16_f32 %0, %1, %2" : "=v"(pk00) : "v"(sc[0][0]), "v"(sc[0][1]));
        asm("v_cvt_pk_bf16_f32 %0, %1, %2" : "=v"(pk01) : "v"(sc[0][2]), "v"(sc[0][3]));
        asm("v_cvt_pk_bf16_f32 %0, %1, %2" : "=v"(pk10) : "v"(sc[1][0]), "v"(sc[1][1]));
        asm("v_cvt_pk_bf16_f32 %0, %1, %2" : "=v"(pk11) : "v"(sc[1][2]), "v"(sc[1][3]));
        asm("v_cvt_pk_bf16_f32 %0, %1, %2" : "=v"(pk20) : "v"(sc[2][0]), "v"(sc[2][1]));
        asm("v_cvt_pk_bf16_f32 %0, %1, %2" : "=v"(pk21) : "v"(sc[2][2]), "v"(sc[2][3]));
        asm("v_cvt_pk_bf16_f32 %0, %1, %2" : "=v"(pk30) : "v"(sc[3][0]), "v"(sc[3][1]));
        asm("v_cvt_pk_bf16_f32 %0, %1, %2" : "=v"(pk31) : "v"(sc[3][2]), "v"(sc[3][3]));
        asm("v_permlane32_swap_b32 %0, %1" : "+v"(pk00), "+v"(pk10));
        asm("v_permlane32_swap_b32 %0, %1" : "+v"(pk01), "+v"(pk11));
        asm("v_permlane32_swap_b32 %0, %1" : "+v"(pk20), "+v"(pk30));
        asm("v_permlane32_swap_b32 %0, %1" : "+v"(pk21), "+v"(pk31));
        union UW { unsigned w[4]; bf16x8 v; };
        UW ua, ub;
        ua.w[0] = pk00; ua.w[1] = pk01; ua.w[2] = pk10; ua.w[3] = pk11;
        ub.w[0] = pk20; ub.w[1] = pk21; ub.w[2] = pk30; ub.w[3] = pk31;
        const bf16x8 pa0 = ua.v, pa1 = ub.v;

        // PV + ones-column row-sum: o[dn] += P*V, ol += P*1
        __builtin_amdgcn_s_setprio(1);
#pragma unroll
        for (int dn = 0; dn < 4; ++dn) {
            bf16x8 vb0 = *(const bf16x8*)(Vc + (fragb0 + dn * 2048));
            bf16x8 vb1 = *(const bf16x8*)(Vc + (fragb1 + dn * 2048));
            o[dn] = __builtin_amdgcn_mfma_f32_16x16x32_bf16(pa0, vb0, o[dn], 0, 0, 0);
            o[dn] = __builtin_amdgcn_mfma_f32_16x16x32_bf16(pa1, vb1, o[dn], 0, 0, 0);
        }
        ol = __builtin_amdgcn_mfma_f32_16x16x32_bf16(pa0, ones, ol, 0, 0, 0);
        ol = __builtin_amdgcn_mfma_f32_16x16x32_bf16(pa1, ones, ol, 0, 0, 0);
        __builtin_amdgcn_s_setprio(0);

        // write-late: commit next tile into the other buffer
        if (more) {
            stK((char*)Kl[cur ^ 1], nk0, nk1);
            stV((char*)Vl[cur ^ 1], nv0, nv1);
        }
        __syncthreads();
        cur ^= 1;
    }

    // epilogue: normalize (ol rows are exactly o's rows -> no shuffles)
    float li[4];
#pragma unroll
    for (int j = 0; j < 4; ++j) li[j] = 1.0f / ol[j];
#pragma unroll
    for (int dn = 0; dn < 4; ++dn)
#pragma unroll
        for (int j = 0; j < 4; ++j) {
            const int row = b * SEQLEN + q0 + wid * 16 + lg * 4 + j;
            attn_out[(size_t)row * EMB + h * 64 + dn * 16 + lr] =
                (bf16_t)(o[dn][j] * li[j]);
        }
}

// ---------------------------------------------------------------------------
extern "C" void kernel_launch(void* const* d_in, const int* in_sizes, int n_in,
                              void* d_out, int out_size, void* d_ws, size_t ws_size,
                              hipStream_t stream)
{
    const float* X     = (const float*)d_in[0];
    const float* W_qkv = (const float*)d_in[1];
    const float* b_qkv = (const float*)d_in[2];
    const float* W_out = (const float*)d_in[3];
    const float* b_out = (const float*)d_in[4];
    float* out = (float*)d_out;

    char* ws = (char*)d_ws;
    bf16_t* Wqkv_t = (bf16_t*)ws;                           //  6 MB [3072][1024]
    bf16_t* Wout_t = (bf16_t*)(ws + 6u * 1024 * 1024);      //  2 MB [1024][1024]
    bf16_t* qkv    = (bf16_t*)(ws + 8u * 1024 * 1024);      // 24 MB [4096][3072] (V region unused)
    bf16_t* attn   = (bf16_t*)(ws + 32u * 1024 * 1024);     //  8 MB [4096][1024]
    bf16_t* Xb     = (bf16_t*)(ws + 40u * 1024 * 1024);     //  8 MB [4096][1024]
    bf16_t* Vt_g   = (bf16_t*)(ws + 48u * 1024 * 1024);     //  8 MB [32][64][2048]

    dim3 blk(256);
    transpose_weights<<<dim3(64, 16), blk, 0, stream>>>(W_qkv, W_out, Wqkv_t, Wout_t);
    cvt_f32_bf16<<<4096 * 1024 / (256 * 8), blk, 0, stream>>>(X, Xb, 4096 * 1024);

    // qkv = X @ W_qkv + b_qkv; V col-blocks written transposed into Vt_g
    gemm_bt_kernel<true, true><<<(4096 / 128) * (N3 / 128), blk, 0, stream>>>(
        Xb, Wqkv_t, b_qkv, (void*)qkv, Vt_g, 1, 4096, N3, EMB);

    // causal flash attention -> attn [4096][1024] bf16
    attn_kernel<<<32 * 32, blk, 0, stream>>>(qkv, Vt_g, attn);

    // out = attn @ W_out + b_out  (fp32 out)
    gemm_bt_kernel<false, false><<<(4096 / 128) * (EMB / 128), blk, 0, stream>>>(
        attn, Wout_t, b_out, (void*)out, nullptr, 0, 4096, EMB, EMB);
}